// Round 4
// baseline (904.188 us; speedup 1.0000x reference)
//
#include <hip/hip_runtime.h>

#define N_NODES 100000
#define F_IN 128
#define HD 16
#define NBKT 782       // buckets of 128 nodes; bucket = dst >> 7
#define NPB 128        // nodes per bucket
#define CHUNK 32768    // edges per workgroup in bucket-build passes

// ---------- pass 1: per-WG LDS histogram over buckets (NO global atomics) ----------
__global__ __launch_bounds__(256) void k_bcnt(const int* __restrict__ dst, int* __restrict__ wgcnt,
                                              int E, int nwg) {
    __shared__ int hist[NBKT];
    const int t = threadIdx.x, wg = blockIdx.x;
    for (int b = t; b < NBKT; b += 256) hist[b] = 0;
    __syncthreads();
    const int e0 = wg * CHUNK;
    for (int it = 0; it < CHUNK / 1024; ++it) {
        int idx = e0 + it * 1024 + t * 4;
        if (idx + 3 < E) {
            int4 d = *(const int4*)(dst + idx);
            atomicAdd(&hist[d.x >> 7], 1);
            atomicAdd(&hist[d.y >> 7], 1);
            atomicAdd(&hist[d.z >> 7], 1);
            atomicAdd(&hist[d.w >> 7], 1);
        } else {
            int lim = min(idx + 4, E);
            for (int e = idx; e < lim; ++e) atomicAdd(&hist[dst[e] >> 7], 1);
        }
    }
    __syncthreads();
    for (int b = t; b < NBKT; b += 256) wgcnt[b * nwg + wg] = hist[b];  // bucket-major
}

// ---------- bucket totals ----------
__global__ __launch_bounds__(128) void k_btot(const int* __restrict__ wgcnt, int* __restrict__ tot, int nwg) {
    __shared__ int s[128];
    const int b = blockIdx.x, t = threadIdx.x;
    s[t] = (t < nwg) ? wgcnt[b * nwg + t] : 0;
    __syncthreads();
    for (int off = 64; off > 0; off >>= 1) { if (t < off) s[t] += s[t + off]; __syncthreads(); }
    if (t == 0) tot[b] = s[0];
}

// ---------- exclusive scan of bucket totals (one WG; NBKT=782 < 1024) ----------
__global__ __launch_bounds__(1024) void k_escan(const int* __restrict__ tot, int* __restrict__ ebase) {
    __shared__ int s[1024];
    const int t = threadIdx.x;
    int v = (t < NBKT) ? tot[t] : 0;
    s[t] = v; __syncthreads();
    for (int off = 1; off < 1024; off <<= 1) {
        int x = (t >= off) ? s[t - off] : 0;
        __syncthreads();
        s[t] += x;
        __syncthreads();
    }
    if (t < NBKT) ebase[t] = s[t] - v;       // exclusive
    if (t == NBKT - 1) ebase[NBKT] = s[t];   // total = E
}

// ---------- per-(bucket, wg) base offsets ----------
__global__ __launch_bounds__(128) void k_bscan(const int* __restrict__ wgcnt, const int* __restrict__ ebase,
                                               int* __restrict__ base, int nwg) {
    __shared__ int s[128];
    const int b = blockIdx.x, t = threadIdx.x;
    int v = (t < nwg) ? wgcnt[b * nwg + t] : 0;
    s[t] = v; __syncthreads();
    for (int off = 1; off < 128; off <<= 1) {
        int x = (t >= off) ? s[t - off] : 0;
        __syncthreads();
        s[t] += x;
        __syncthreads();
    }
    if (t < nwg) base[b * nwg + t] = ebase[b] + s[t] - v;
}

// ---------- pass 2: scatter with LDS cursors; writes have ~170B/bucket locality ----------
__global__ __launch_bounds__(256) void k_bscatter(const int* __restrict__ src, const int* __restrict__ dst,
                                                  const int* __restrict__ base, unsigned* __restrict__ srt,
                                                  int E, int nwg) {
    __shared__ int cur[NBKT];
    const int t = threadIdx.x, wg = blockIdx.x;
    for (int b = t; b < NBKT; b += 256) cur[b] = base[b * nwg + wg];
    __syncthreads();
    const int e0 = wg * CHUNK;
    for (int it = 0; it < CHUNK / 1024; ++it) {
        int idx = e0 + it * 1024 + t * 4;
        if (idx + 3 < E) {
            int4 s4 = *(const int4*)(src + idx);
            int4 d4 = *(const int4*)(dst + idx);
            int p;
            p = atomicAdd(&cur[d4.x >> 7], 1); srt[p] = ((unsigned)s4.x << 7) | (unsigned)(d4.x & 127);
            p = atomicAdd(&cur[d4.y >> 7], 1); srt[p] = ((unsigned)s4.y << 7) | (unsigned)(d4.y & 127);
            p = atomicAdd(&cur[d4.z >> 7], 1); srt[p] = ((unsigned)s4.z << 7) | (unsigned)(d4.z & 127);
            p = atomicAdd(&cur[d4.w >> 7], 1); srt[p] = ((unsigned)s4.w << 7) | (unsigned)(d4.w & 127);
        } else {
            int lim = min(idx + 4, E);
            for (int e = idx; e < lim; ++e) {
                int p = atomicAdd(&cur[dst[e] >> 7], 1);
                srt[p] = ((unsigned)src[e] << 7) | (unsigned)(dst[e] & 127);
            }
        }
    }
}

// ---------- per-bucket degrees -> dinv (LDS counters only) ----------
__global__ __launch_bounds__(256) void k_deg(const unsigned* __restrict__ srt, const int* __restrict__ ebase,
                                             float* __restrict__ dinv) {
    __shared__ int cnt[NPB];
    const int t = threadIdx.x, b = blockIdx.x;
    if (t < NPB) cnt[t] = 0;
    __syncthreads();
    const int beg = ebase[b], end = ebase[b + 1];
    for (int i = beg + t; i < end; i += 256) atomicAdd(&cnt[srt[i] & 127], 1);
    __syncthreads();
    if (t < NPB) {
        int node = b * NPB + t;
        if (node < N_NODES) dinv[node] = rsqrtf((float)(cnt[t] + 1));  // +1 self-loop
    }
}

// ---------- dense layer 1: hs1 = dinv * (x @ W1) ----------
__global__ __launch_bounds__(256) void k_h1(
        const float* __restrict__ x, const float* __restrict__ W1,
        const float* __restrict__ dinv, float* __restrict__ hs) {
    __shared__ float ws[F_IN * HD];
    __shared__ float xs[16][F_IN + 1];
    const int t = threadIdx.x;
    const int node0 = blockIdx.x * 16;

    for (int i = t; i < F_IN * HD; i += 256) ws[i] = W1[i];
    for (int i = t; i < 16 * F_IN; i += 256) {
        int r = i >> 7, c = i & 127;
        int n = node0 + r;
        xs[r][c] = (n < N_NODES) ? x[n * F_IN + c] : 0.0f;
    }
    __syncthreads();

    const int row = t >> 4, col = t & 15;
    const int node = node0 + row;
    float acc = 0.0f;
#pragma unroll 8
    for (int k = 0; k < F_IN; ++k)
        acc += xs[row][k] * ws[k * HD + col];

    if (node < N_NODES) hs[node * HD + col] = acc * dinv[node];
}

// ---------- dense layer 2: hs2 = dinv * (relu(out1) @ W2) ----------
__global__ __launch_bounds__(256) void k_h2(
        const float* __restrict__ out1, const float* __restrict__ W2,
        const float* __restrict__ dinv, float* __restrict__ hs) {
    __shared__ float ws[HD * HD];
    __shared__ float as[16][HD + 1];
    const int t = threadIdx.x;
    const int node0 = blockIdx.x * 16;

    if (t < HD * HD) ws[t] = W2[t];
    {
        int n = node0 + (t >> 4);
        float v = (n < N_NODES) ? out1[node0 * HD + t] : 0.0f;
        as[t >> 4][t & 15] = fmaxf(v, 0.0f);
    }
    __syncthreads();

    const int row = t >> 4, col = t & 15;
    const int node = node0 + row;
    float acc = 0.0f;
#pragma unroll
    for (int k = 0; k < HD; ++k)
        acc += as[row][k] * ws[k * HD + col];

    if (node < N_NODES) hs[node * HD + col] = acc * dinv[node];
}

// ---------- aggregation: one WG per bucket, LDS f32 accumulator, NO global atomics ----------
// out[d] = dinv[d] * ( sum_{s in N(d)} hs[s] + hs[d] ) + bias
__global__ __launch_bounds__(256) void k_agg(const unsigned* __restrict__ srt, const int* __restrict__ ebase,
                                             const float* __restrict__ dinv, const float* __restrict__ hs,
                                             const float* __restrict__ bias, float* __restrict__ out) {
    __shared__ float acc[NPB * HD];   // 8 KB
    const int t = threadIdx.x, b = blockIdx.x;
    for (int i = t; i < NPB * HD; i += 256) acc[i] = 0.0f;
    __syncthreads();

    const int beg = ebase[b];
    const int cnt = ebase[b + 1] - beg;
    const int c = t & 15, slot = t >> 4;    // 16 slots x 16 feature lanes

    for (int i = slot * 2; i < cnt; i += 32) {   // 2 edges per slot per iter (ILP)
        unsigned p0 = srt[beg + i];
        float v0 = hs[(p0 >> 7) * HD + c];       // 64B coalesced gather per 16-lane group
        int j = i + 1;
        if (j < cnt) {
            unsigned p1 = srt[beg + j];
            float v1 = hs[(p1 >> 7) * HD + c];
            atomicAdd(&acc[(p0 & 127) * HD + c], v0);
            atomicAdd(&acc[(p1 & 127) * HD + c], v1);
        } else {
            atomicAdd(&acc[(p0 & 127) * HD + c], v0);
        }
    }
    __syncthreads();

    for (int l = slot; l < NPB; l += 16) {
        int node = b * NPB + l;
        if (node < N_NODES)
            out[node * HD + c] = dinv[node] * (acc[l * HD + c] + hs[node * HD + c]) + bias[c];
    }
}

// ---------------- launch ----------------
extern "C" void kernel_launch(void* const* d_in, const int* in_sizes, int n_in,
                              void* d_out, int out_size, void* d_ws, size_t ws_size,
                              hipStream_t stream) {
    const float* x   = (const float*)d_in[0];
    const int*   ei  = (const int*)d_in[1];
    const float* W1  = (const float*)d_in[2];
    const float* b1  = (const float*)d_in[3];
    const float* W2  = (const float*)d_in[4];
    const float* b2  = (const float*)d_in[5];
    float* out = (float*)d_out;

    const int E = in_sizes[1] / 2;
    const int* src = ei;
    const int* dst = ei + E;
    const int nwg = (E + CHUNK - 1) / CHUNK;   // 98 for E=3.2M

    // workspace layout (bytes)
    char* wsb = (char*)d_ws;
    int*      wgcnt = (int*)(wsb + 0x0000000);   // NBKT*nwg ints (~306 KB)
    int*      base  = (int*)(wsb + 0x0060000);   // NBKT*nwg ints
    int*      tot   = (int*)(wsb + 0x00C0000);   // NBKT ints
    int*      ebase = (int*)(wsb + 0x00C2000);   // NBKT+1 ints
    float*    dinv  = (float*)(wsb + 0x00D0000); // 400 KB
    float*    hs    = (float*)(wsb + 0x0200000); // 6.4 MB (hs1, reused as hs2)
    float*    out1  = (float*)(wsb + 0x0900000); // 6.4 MB
    unsigned* srt   = (unsigned*)(wsb + 0x1000000); // 12.8 MB packed edges

    const int tileBlocks = (N_NODES + 15) / 16;

    // bucket-CSR build (atomic-free at global scope; reused by both layers)
    k_bcnt<<<nwg, 256, 0, stream>>>(dst, wgcnt, E, nwg);
    k_btot<<<NBKT, 128, 0, stream>>>(wgcnt, tot, nwg);
    k_escan<<<1, 1024, 0, stream>>>(tot, ebase);
    k_bscan<<<NBKT, 128, 0, stream>>>(wgcnt, ebase, base, nwg);
    k_bscatter<<<nwg, 256, 0, stream>>>(src, dst, base, srt, E, nwg);
    k_deg<<<NBKT, 256, 0, stream>>>(srt, ebase, dinv);

    // layer 1
    k_h1<<<tileBlocks, 256, 0, stream>>>(x, W1, dinv, hs);
    k_agg<<<NBKT, 256, 0, stream>>>(srt, ebase, dinv, hs, b1, out1);

    // layer 2
    k_h2<<<tileBlocks, 256, 0, stream>>>(out1, W2, dinv, hs);
    k_agg<<<NBKT, 256, 0, stream>>>(srt, ebase, dinv, hs, b2, out);
}

// Round 5
// 305.721 us; speedup vs baseline: 2.9576x; 2.9576x over previous
//
#include <hip/hip_runtime.h>

#define N_NODES 100000
#define F_IN 128
#define HD 16
#define NBKT 782       // buckets of 128 nodes; bucket = dst >> 7
#define NPB 128        // nodes per bucket
#define CHUNK 32768    // edges per workgroup in bucket-build passes

// ---------- pass 1: per-WG LDS histogram over buckets (NO global atomics) ----------
__global__ __launch_bounds__(256) void k_bcnt(const int* __restrict__ dst, int* __restrict__ wgcnt,
                                              int E, int nwg) {
    __shared__ int hist[NBKT];
    const int t = threadIdx.x, wg = blockIdx.x;
    for (int b = t; b < NBKT; b += 256) hist[b] = 0;
    __syncthreads();
    const int e0 = wg * CHUNK;
    for (int it = 0; it < CHUNK / 1024; ++it) {
        int idx = e0 + it * 1024 + t * 4;
        if (idx + 3 < E) {
            int4 d = *(const int4*)(dst + idx);
            atomicAdd(&hist[d.x >> 7], 1);
            atomicAdd(&hist[d.y >> 7], 1);
            atomicAdd(&hist[d.z >> 7], 1);
            atomicAdd(&hist[d.w >> 7], 1);
        } else {
            int lim = min(idx + 4, E);
            for (int e = idx; e < lim; ++e) atomicAdd(&hist[dst[e] >> 7], 1);
        }
    }
    __syncthreads();
    for (int b = t; b < NBKT; b += 256) wgcnt[b * nwg + wg] = hist[b];  // bucket-major
}

// ---------- bucket totals ----------
__global__ __launch_bounds__(128) void k_btot(const int* __restrict__ wgcnt, int* __restrict__ tot, int nwg) {
    __shared__ int s[128];
    const int b = blockIdx.x, t = threadIdx.x;
    s[t] = (t < nwg) ? wgcnt[b * nwg + t] : 0;
    __syncthreads();
    for (int off = 64; off > 0; off >>= 1) { if (t < off) s[t] += s[t + off]; __syncthreads(); }
    if (t == 0) tot[b] = s[0];
}

// ---------- exclusive scan of bucket totals (one WG; NBKT=782 < 1024) ----------
__global__ __launch_bounds__(1024) void k_escan(const int* __restrict__ tot, int* __restrict__ ebase) {
    __shared__ int s[1024];
    const int t = threadIdx.x;
    int v = (t < NBKT) ? tot[t] : 0;
    s[t] = v; __syncthreads();
    for (int off = 1; off < 1024; off <<= 1) {
        int x = (t >= off) ? s[t - off] : 0;
        __syncthreads();
        s[t] += x;
        __syncthreads();
    }
    if (t < NBKT) ebase[t] = s[t] - v;       // exclusive
    if (t == NBKT - 1) ebase[NBKT] = s[t];   // total = E
}

// ---------- per-(bucket, wg) base offsets ----------
__global__ __launch_bounds__(128) void k_bscan(const int* __restrict__ wgcnt, const int* __restrict__ ebase,
                                               int* __restrict__ base, int nwg) {
    __shared__ int s[128];
    const int b = blockIdx.x, t = threadIdx.x;
    int v = (t < nwg) ? wgcnt[b * nwg + t] : 0;
    s[t] = v; __syncthreads();
    for (int off = 1; off < 128; off <<= 1) {
        int x = (t >= off) ? s[t - off] : 0;
        __syncthreads();
        s[t] += x;
        __syncthreads();
    }
    if (t < nwg) base[b * nwg + t] = ebase[b] + s[t] - v;
}

// ---------- pass 2: scatter into bucket-sorted order (LDS cursors) ----------
__global__ __launch_bounds__(256) void k_bscatter(const int* __restrict__ src, const int* __restrict__ dst,
                                                  const int* __restrict__ base, unsigned* __restrict__ srt,
                                                  int E, int nwg) {
    __shared__ int cur[NBKT];
    const int t = threadIdx.x, wg = blockIdx.x;
    for (int b = t; b < NBKT; b += 256) cur[b] = base[b * nwg + wg];
    __syncthreads();
    const int e0 = wg * CHUNK;
    for (int it = 0; it < CHUNK / 1024; ++it) {
        int idx = e0 + it * 1024 + t * 4;
        if (idx + 3 < E) {
            int4 s4 = *(const int4*)(src + idx);
            int4 d4 = *(const int4*)(dst + idx);
            int p;
            p = atomicAdd(&cur[d4.x >> 7], 1); srt[p] = ((unsigned)s4.x << 7) | (unsigned)(d4.x & 127);
            p = atomicAdd(&cur[d4.y >> 7], 1); srt[p] = ((unsigned)s4.y << 7) | (unsigned)(d4.y & 127);
            p = atomicAdd(&cur[d4.z >> 7], 1); srt[p] = ((unsigned)s4.z << 7) | (unsigned)(d4.z & 127);
            p = atomicAdd(&cur[d4.w >> 7], 1); srt[p] = ((unsigned)s4.w << 7) | (unsigned)(d4.w & 127);
        } else {
            int lim = min(idx + 4, E);
            for (int e = idx; e < lim; ++e) {
                int p = atomicAdd(&cur[dst[e] >> 7], 1);
                srt[p] = ((unsigned)src[e] << 7) | (unsigned)(dst[e] & 127);
            }
        }
    }
}

// ---------- pass 3: in-bucket counting sort -> node-level CSR (srt2, rs, dinv) ----------
// One WG per bucket. All counters/cursors in LDS; writes stay within the bucket's
// contiguous ~16KB region of srt2 (L2-absorbed). No global atomics.
__global__ __launch_bounds__(256) void k_bsort(const unsigned* __restrict__ srt,
                                               const int* __restrict__ ebase,
                                               int* __restrict__ srt2,
                                               int* __restrict__ rs,
                                               float* __restrict__ dinv) {
    __shared__ int cnt_s[NPB];
    __shared__ int sc[NPB];
    __shared__ int cur_s[NPB];
    const int t = threadIdx.x, b = blockIdx.x;
    const int beg = ebase[b], end = ebase[b + 1];

    if (t < NPB) cnt_s[t] = 0;
    __syncthreads();
    for (int i = beg + t; i < end; i += 256) atomicAdd(&cnt_s[srt[i] & 127], 1);
    __syncthreads();

    if (t < NPB) sc[t] = cnt_s[t];
    __syncthreads();
    for (int off = 1; off < NPB; off <<= 1) {
        int v = (t < NPB && t >= off) ? sc[t - off] : 0;
        __syncthreads();
        if (t < NPB) sc[t] += v;
        __syncthreads();
    }
    if (t < NPB) {
        int start = beg + sc[t] - cnt_s[t];   // exclusive
        cur_s[t] = start;
        int node = b * NPB + t;
        if (node <= N_NODES) rs[node] = start;  // node==N_NODES lands here (last bucket) -> E
        if (node < N_NODES) dinv[node] = rsqrtf((float)(cnt_s[t] + 1));  // +1 self-loop
    }
    __syncthreads();
    for (int i = beg + t; i < end; i += 256) {
        unsigned p = srt[i];
        int pos = atomicAdd(&cur_s[p & 127], 1);
        srt2[pos] = (int)(p >> 7);            // plain src, dst-sorted
    }
}

// ---------- dense layer 1: hs1 = dinv * (x @ W1) ----------
__global__ __launch_bounds__(256) void k_h1(
        const float* __restrict__ x, const float* __restrict__ W1,
        const float* __restrict__ dinv, float* __restrict__ hs) {
    __shared__ float ws[F_IN * HD];
    __shared__ float xs[16][F_IN + 1];
    const int t = threadIdx.x;
    const int node0 = blockIdx.x * 16;

    for (int i = t; i < F_IN * HD; i += 256) ws[i] = W1[i];
    for (int i = t; i < 16 * F_IN; i += 256) {
        int r = i >> 7, c = i & 127;
        int n = node0 + r;
        xs[r][c] = (n < N_NODES) ? x[n * F_IN + c] : 0.0f;
    }
    __syncthreads();

    const int row = t >> 4, col = t & 15;
    const int node = node0 + row;
    float acc = 0.0f;
#pragma unroll 8
    for (int k = 0; k < F_IN; ++k)
        acc += xs[row][k] * ws[k * HD + col];

    if (node < N_NODES) hs[node * HD + col] = acc * dinv[node];
}

// ---------- dense layer 2: hs2 = dinv * (relu(out1) @ W2) ----------
__global__ __launch_bounds__(256) void k_h2(
        const float* __restrict__ out1, const float* __restrict__ W2,
        const float* __restrict__ dinv, float* __restrict__ hs) {
    __shared__ float ws[HD * HD];
    __shared__ float as[16][HD + 1];
    const int t = threadIdx.x;
    const int node0 = blockIdx.x * 16;

    if (t < HD * HD) ws[t] = W2[t];
    {
        int n = node0 + (t >> 4);
        float v = (n < N_NODES) ? out1[node0 * HD + t] : 0.0f;
        as[t >> 4][t & 15] = fmaxf(v, 0.0f);
    }
    __syncthreads();

    const int row = t >> 4, col = t & 15;
    const int node = node0 + row;
    float acc = 0.0f;
#pragma unroll
    for (int k = 0; k < HD; ++k)
        acc += as[row][k] * ws[k * HD + col];

    if (node < N_NODES) hs[node * HD + col] = acc * dinv[node];
}

// ---------- aggregation: one wave per node, no LDS, no atomics ----------
// 16 edge-slots x 4-lane float4 feature-quads = 16 outstanding 64B gathers/wave.
// out[d] = dinv[d] * ( sum_{s in N(d)} hs[s] + hs[d] ) + bias
__global__ __launch_bounds__(256) void k_agg(
        const int* __restrict__ srt2, const int* __restrict__ rs,
        const float* __restrict__ dinv, const float* __restrict__ hs,
        const float* __restrict__ bias, float* __restrict__ out) {
    const int node = blockIdx.x * 4 + (threadIdx.x >> 6);
    if (node >= N_NODES) return;   // wave-uniform
    const int lane = threadIdx.x & 63;
    const int slot = lane >> 2;    // 16 edge slots
    const int c4 = lane & 3;       // feature quad (4 floats)

    const int beg = rs[node];
    const int n   = rs[node + 1] - beg;
    const float4* __restrict__ h4 = (const float4*)hs;

    float4 a = make_float4(0.0f, 0.0f, 0.0f, 0.0f);
    for (int i = slot; i < n; i += 16) {
        int s = srt2[beg + i];         // 16 slots read 64B coalesced; broadcast within quad
        float4 v = h4[s * 4 + c4];     // 4 lanes fetch one contiguous 64B row
        a.x += v.x; a.y += v.y; a.z += v.z; a.w += v.w;
    }
#pragma unroll
    for (int m = 4; m <= 32; m <<= 1) {
        a.x += __shfl_xor(a.x, m);
        a.y += __shfl_xor(a.y, m);
        a.z += __shfl_xor(a.z, m);
        a.w += __shfl_xor(a.w, m);
    }
    if (slot == 0) {
        float4 hv = h4[node * 4 + c4];
        float4 bb = ((const float4*)bias)[c4];
        float dd = dinv[node];
        float4 o;
        o.x = dd * (a.x + hv.x) + bb.x;
        o.y = dd * (a.y + hv.y) + bb.y;
        o.z = dd * (a.z + hv.z) + bb.z;
        o.w = dd * (a.w + hv.w) + bb.w;
        ((float4*)out)[node * 4 + c4] = o;
    }
}

// ---------------- launch ----------------
extern "C" void kernel_launch(void* const* d_in, const int* in_sizes, int n_in,
                              void* d_out, int out_size, void* d_ws, size_t ws_size,
                              hipStream_t stream) {
    const float* x   = (const float*)d_in[0];
    const int*   ei  = (const int*)d_in[1];
    const float* W1  = (const float*)d_in[2];
    const float* b1  = (const float*)d_in[3];
    const float* W2  = (const float*)d_in[4];
    const float* b2  = (const float*)d_in[5];
    float* out = (float*)d_out;

    const int E = in_sizes[1] / 2;
    const int* src = ei;
    const int* dst = ei + E;
    const int nwg = (E + CHUNK - 1) / CHUNK;   // 98 for E=3.2M

    // workspace layout (bytes). NOTE aliasing: srt (pass-A output) is dead after
    // k_bsort; hs/out1 reuse its region.
    char* wsb = (char*)d_ws;
    int*      wgcnt = (int*)(wsb + 0x0000000);     // NBKT*nwg ints (~306 KB)
    int*      base  = (int*)(wsb + 0x0060000);     // NBKT*nwg ints
    int*      tot   = (int*)(wsb + 0x00C0000);     // NBKT ints
    int*      ebase = (int*)(wsb + 0x00C2000);     // NBKT+1 ints
    float*    dinv  = (float*)(wsb + 0x00D0000);   // 400 KB
    int*      rs    = (int*)(wsb + 0x0140000);     // (N+1) ints, 400 KB
    unsigned* srt   = (unsigned*)(wsb + 0x0200000); // 12.8 MB packed edges (dead after k_bsort)
    float*    hs    = (float*)(wsb + 0x0200000);   // 6.4 MB (aliases srt; written after k_bsort)
    float*    out1  = (float*)(wsb + 0x0900000);   // 6.4 MB (aliases srt tail)
    int*      srt2  = (int*)(wsb + 0x1000000);     // 12.8 MB dst-sorted src

    const int tileBlocks = (N_NODES + 15) / 16;
    const int aggBlocks  = (N_NODES + 3) / 4;

    // node-CSR build (atomic-free at global scope; reused by both layers)
    k_bcnt<<<nwg, 256, 0, stream>>>(dst, wgcnt, E, nwg);
    k_btot<<<NBKT, 128, 0, stream>>>(wgcnt, tot, nwg);
    k_escan<<<1, 1024, 0, stream>>>(tot, ebase);
    k_bscan<<<NBKT, 128, 0, stream>>>(wgcnt, ebase, base, nwg);
    k_bscatter<<<nwg, 256, 0, stream>>>(src, dst, base, srt, E, nwg);
    k_bsort<<<NBKT, 256, 0, stream>>>(srt, ebase, srt2, rs, dinv);

    // layer 1
    k_h1<<<tileBlocks, 256, 0, stream>>>(x, W1, dinv, hs);
    k_agg<<<aggBlocks, 256, 0, stream>>>(srt2, rs, dinv, hs, b1, out1);

    // layer 2
    k_h2<<<tileBlocks, 256, 0, stream>>>(out1, W2, dinv, hs);
    k_agg<<<aggBlocks, 256, 0, stream>>>(srt2, rs, dinv, hs, b2, out);
}

// Round 6
// 283.910 us; speedup vs baseline: 3.1848x; 1.0768x over previous
//
#include <hip/hip_runtime.h>
#include <hip/hip_fp16.h>

#define N_NODES 100000
#define F_IN 128
#define HD 16
#define NBKT 782       // buckets of 128 nodes; bucket = dst >> 7
#define NPB 128        // nodes per bucket
#define CHUNK 8192     // edges per workgroup in bucket-build passes (nwg = 391)
#define BTHREADS 512   // threads per build-pass workgroup (8 waves)

typedef __attribute__((ext_vector_type(4))) _Float16 half4;

// ---------- pass 1: per-WG LDS histogram over buckets (NO global atomics) ----------
__global__ __launch_bounds__(BTHREADS) void k_bcnt(const int* __restrict__ dst, int* __restrict__ wgcnt,
                                                   int E, int nwg) {
    __shared__ int hist[NBKT];
    const int t = threadIdx.x, wg = blockIdx.x;
    for (int b = t; b < NBKT; b += BTHREADS) hist[b] = 0;
    __syncthreads();
    const int e0 = wg * CHUNK;
    for (int it = 0; it < CHUNK / (BTHREADS * 4); ++it) {
        int idx = e0 + it * (BTHREADS * 4) + t * 4;
        if (idx + 3 < E) {
            int4 d = *(const int4*)(dst + idx);
            atomicAdd(&hist[d.x >> 7], 1);
            atomicAdd(&hist[d.y >> 7], 1);
            atomicAdd(&hist[d.z >> 7], 1);
            atomicAdd(&hist[d.w >> 7], 1);
        } else {
            int lim = min(idx + 4, E);
            for (int e = idx; e < lim; ++e) atomicAdd(&hist[dst[e] >> 7], 1);
        }
    }
    __syncthreads();
    for (int b = t; b < NBKT; b += BTHREADS) wgcnt[b * nwg + wg] = hist[b];  // bucket-major
}

// ---------- bucket totals (nwg <= 512) ----------
__global__ __launch_bounds__(512) void k_btot(const int* __restrict__ wgcnt, int* __restrict__ tot, int nwg) {
    __shared__ int s[512];
    const int b = blockIdx.x, t = threadIdx.x;
    s[t] = (t < nwg) ? wgcnt[b * nwg + t] : 0;
    __syncthreads();
    for (int off = 256; off > 0; off >>= 1) { if (t < off) s[t] += s[t + off]; __syncthreads(); }
    if (t == 0) tot[b] = s[0];
}

// ---------- exclusive scan of bucket totals (one WG; NBKT=782 < 1024) ----------
__global__ __launch_bounds__(1024) void k_escan(const int* __restrict__ tot, int* __restrict__ ebase) {
    __shared__ int s[1024];
    const int t = threadIdx.x;
    int v = (t < NBKT) ? tot[t] : 0;
    s[t] = v; __syncthreads();
    for (int off = 1; off < 1024; off <<= 1) {
        int x = (t >= off) ? s[t - off] : 0;
        __syncthreads();
        s[t] += x;
        __syncthreads();
    }
    if (t < NBKT) ebase[t] = s[t] - v;       // exclusive
    if (t == NBKT - 1) ebase[NBKT] = s[t];   // total = E
}

// ---------- per-(bucket, wg) base offsets (nwg <= 512) ----------
__global__ __launch_bounds__(512) void k_bscan(const int* __restrict__ wgcnt, const int* __restrict__ ebase,
                                               int* __restrict__ base, int nwg) {
    __shared__ int s[512];
    const int b = blockIdx.x, t = threadIdx.x;
    int v = (t < nwg) ? wgcnt[b * nwg + t] : 0;
    s[t] = v; __syncthreads();
    for (int off = 1; off < 512; off <<= 1) {
        int x = (t >= off) ? s[t - off] : 0;
        __syncthreads();
        s[t] += x;
        __syncthreads();
    }
    if (t < nwg) base[b * nwg + t] = ebase[b] + s[t] - v;
}

// ---------- pass 2: scatter into bucket-sorted order (LDS cursors) ----------
__global__ __launch_bounds__(BTHREADS) void k_bscatter(const int* __restrict__ src, const int* __restrict__ dst,
                                                       const int* __restrict__ base, unsigned* __restrict__ srt,
                                                       int E, int nwg) {
    __shared__ int cur[NBKT];
    const int t = threadIdx.x, wg = blockIdx.x;
    for (int b = t; b < NBKT; b += BTHREADS) cur[b] = base[b * nwg + wg];
    __syncthreads();
    const int e0 = wg * CHUNK;
    for (int it = 0; it < CHUNK / (BTHREADS * 4); ++it) {
        int idx = e0 + it * (BTHREADS * 4) + t * 4;
        if (idx + 3 < E) {
            int4 s4 = *(const int4*)(src + idx);
            int4 d4 = *(const int4*)(dst + idx);
            int p;
            p = atomicAdd(&cur[d4.x >> 7], 1); srt[p] = ((unsigned)s4.x << 7) | (unsigned)(d4.x & 127);
            p = atomicAdd(&cur[d4.y >> 7], 1); srt[p] = ((unsigned)s4.y << 7) | (unsigned)(d4.y & 127);
            p = atomicAdd(&cur[d4.z >> 7], 1); srt[p] = ((unsigned)s4.z << 7) | (unsigned)(d4.z & 127);
            p = atomicAdd(&cur[d4.w >> 7], 1); srt[p] = ((unsigned)s4.w << 7) | (unsigned)(d4.w & 127);
        } else {
            int lim = min(idx + 4, E);
            for (int e = idx; e < lim; ++e) {
                int p = atomicAdd(&cur[dst[e] >> 7], 1);
                srt[p] = ((unsigned)src[e] << 7) | (unsigned)(dst[e] & 127);
            }
        }
    }
}

// ---------- pass 3: in-bucket counting sort -> node-level CSR (srt2, rs, dinv) ----------
__global__ __launch_bounds__(256) void k_bsort(const unsigned* __restrict__ srt,
                                               const int* __restrict__ ebase,
                                               int* __restrict__ srt2,
                                               int* __restrict__ rs,
                                               float* __restrict__ dinv) {
    __shared__ int cnt_s[NPB];
    __shared__ int sc[NPB];
    __shared__ int cur_s[NPB];
    const int t = threadIdx.x, b = blockIdx.x;
    const int beg = ebase[b], end = ebase[b + 1];

    if (t < NPB) cnt_s[t] = 0;
    __syncthreads();
    for (int i = beg + t; i < end; i += 256) atomicAdd(&cnt_s[srt[i] & 127], 1);
    __syncthreads();

    if (t < NPB) sc[t] = cnt_s[t];
    __syncthreads();
    for (int off = 1; off < NPB; off <<= 1) {
        int v = (t < NPB && t >= off) ? sc[t - off] : 0;
        __syncthreads();
        if (t < NPB) sc[t] += v;
        __syncthreads();
    }
    if (t < NPB) {
        int start = beg + sc[t] - cnt_s[t];   // exclusive
        cur_s[t] = start;
        int node = b * NPB + t;
        if (node <= N_NODES) rs[node] = start;  // node==N_NODES (last bucket) -> E
        if (node < N_NODES) dinv[node] = rsqrtf((float)(cnt_s[t] + 1));  // +1 self-loop
    }
    __syncthreads();
    for (int i = beg + t; i < end; i += 256) {
        unsigned p = srt[i];
        int pos = atomicAdd(&cur_s[p & 127], 1);
        srt2[pos] = (int)(p >> 7);            // plain src, dst-sorted
    }
}

// ---------- dense layer 1: hs1 = fp16( dinv * (x @ W1) ) ----------
__global__ __launch_bounds__(256) void k_h1(
        const float* __restrict__ x, const float* __restrict__ W1,
        const float* __restrict__ dinv, _Float16* __restrict__ hs) {
    __shared__ float ws[F_IN * HD];
    __shared__ float xs[16][F_IN + 1];
    const int t = threadIdx.x;
    const int node0 = blockIdx.x * 16;

    for (int i = t; i < F_IN * HD; i += 256) ws[i] = W1[i];
    for (int i = t; i < 16 * F_IN; i += 256) {
        int r = i >> 7, c = i & 127;
        int n = node0 + r;
        xs[r][c] = (n < N_NODES) ? x[n * F_IN + c] : 0.0f;
    }
    __syncthreads();

    const int row = t >> 4, col = t & 15;
    const int node = node0 + row;
    float acc = 0.0f;
#pragma unroll 8
    for (int k = 0; k < F_IN; ++k)
        acc += xs[row][k] * ws[k * HD + col];

    if (node < N_NODES) hs[node * HD + col] = (_Float16)(acc * dinv[node]);
}

// ---------- dense layer 2: hs2 = fp16( dinv * (relu(out1) @ W2) ) ----------
__global__ __launch_bounds__(256) void k_h2(
        const float* __restrict__ out1, const float* __restrict__ W2,
        const float* __restrict__ dinv, _Float16* __restrict__ hs) {
    __shared__ float ws[HD * HD];
    __shared__ float as[16][HD + 1];
    const int t = threadIdx.x;
    const int node0 = blockIdx.x * 16;

    if (t < HD * HD) ws[t] = W2[t];
    {
        int n = node0 + (t >> 4);
        float v = (n < N_NODES) ? out1[node0 * HD + t] : 0.0f;
        as[t >> 4][t & 15] = fmaxf(v, 0.0f);
    }
    __syncthreads();

    const int row = t >> 4, col = t & 15;
    const int node = node0 + row;
    float acc = 0.0f;
#pragma unroll
    for (int k = 0; k < HD; ++k)
        acc += as[row][k] * ws[k * HD + col];

    if (node < N_NODES) hs[node * HD + col] = (_Float16)(acc * dinv[node]);
}

// ---------- aggregation: one wave per node, fp16 gathers, f32 accumulate ----------
// 16 edge-slots x 4-lane 8B feature-quads = 16 outstanding 32B row-gathers/wave.
// out[d] = dinv[d] * ( sum_{s in N(d)} hs[s] + hs[d] ) + bias
__global__ __launch_bounds__(256) void k_agg(
        const int* __restrict__ srt2, const int* __restrict__ rs,
        const float* __restrict__ dinv, const _Float16* __restrict__ hs,
        const float* __restrict__ bias, float* __restrict__ out) {
    const int node = blockIdx.x * 4 + (threadIdx.x >> 6);
    if (node >= N_NODES) return;   // wave-uniform
    const int lane = threadIdx.x & 63;
    const int slot = lane >> 2;    // 16 edge slots
    const int c4 = lane & 3;       // feature quad (4 halves = 8B)

    const int beg = rs[node];
    const int n   = rs[node + 1] - beg;
    const half4* __restrict__ h4 = (const half4*)hs;

    float ax = 0.0f, ay = 0.0f, az = 0.0f, aw = 0.0f;
    for (int i = slot; i < n; i += 16) {
        int s = srt2[beg + i];         // 16 slots read 64B coalesced; broadcast within quad
        half4 v = h4[s * 4 + c4];      // 4 lanes fetch one contiguous 32B row
        ax += (float)v.x; ay += (float)v.y; az += (float)v.z; aw += (float)v.w;
    }
#pragma unroll
    for (int m = 4; m <= 32; m <<= 1) {
        ax += __shfl_xor(ax, m);
        ay += __shfl_xor(ay, m);
        az += __shfl_xor(az, m);
        aw += __shfl_xor(aw, m);
    }
    if (slot == 0) {
        half4 hv = h4[node * 4 + c4];
        float4 bb = ((const float4*)bias)[c4];
        float dd = dinv[node];
        float4 o;
        o.x = dd * (ax + (float)hv.x) + bb.x;
        o.y = dd * (ay + (float)hv.y) + bb.y;
        o.z = dd * (az + (float)hv.z) + bb.z;
        o.w = dd * (aw + (float)hv.w) + bb.w;
        ((float4*)out)[node * 4 + c4] = o;
    }
}

// ---------------- launch ----------------
extern "C" void kernel_launch(void* const* d_in, const int* in_sizes, int n_in,
                              void* d_out, int out_size, void* d_ws, size_t ws_size,
                              hipStream_t stream) {
    const float* x   = (const float*)d_in[0];
    const int*   ei  = (const int*)d_in[1];
    const float* W1  = (const float*)d_in[2];
    const float* b1  = (const float*)d_in[3];
    const float* W2  = (const float*)d_in[4];
    const float* b2  = (const float*)d_in[5];
    float* out = (float*)d_out;

    const int E = in_sizes[1] / 2;
    const int* src = ei;
    const int* dst = ei + E;
    const int nwg = (E + CHUNK - 1) / CHUNK;   // 391 for E=3.2M

    // workspace layout (bytes). Aliasing:
    //  - srt  [0x100000, +12.8MB) is dead after k_bsort; hs (fp16, 3.2MB) and
    //    out1 (f32, 6.4MB) reuse its region afterwards.
    //  - wgcnt/base live inside srt2's region; both dead before k_bsort writes srt2.
    char* wsb = (char*)d_ws;
    int*      tot   = (int*)(wsb + 0x0000000);      // NBKT ints
    int*      ebase = (int*)(wsb + 0x0001000);      // NBKT+1 ints
    float*    dinv  = (float*)(wsb + 0x0002000);    // 400 KB
    int*      rs    = (int*)(wsb + 0x0070000);      // (N+1) ints, 400 KB
    unsigned* srt   = (unsigned*)(wsb + 0x0100000); // 12.8 MB packed edges
    _Float16* hs    = (_Float16*)(wsb + 0x0100000); // 3.2 MB (aliases srt, written after k_bsort)
    float*    out1  = (float*)(wsb + 0x0500000);    // 6.4 MB (aliases srt tail)
    int*      srt2  = (int*)(wsb + 0x0D40000);      // 12.8 MB dst-sorted src
    int*      wgcnt = (int*)(wsb + 0x0D40000);      // NBKT*nwg ints (~1.2 MB; dead before srt2 written)
    int*      base  = (int*)(wsb + 0x0F00000);      // NBKT*nwg ints (~1.2 MB; dead before srt2 written)

    const int tileBlocks = (N_NODES + 15) / 16;
    const int aggBlocks  = (N_NODES + 3) / 4;

    // node-CSR build (atomic-free at global scope; reused by both layers)
    k_bcnt<<<nwg, BTHREADS, 0, stream>>>(dst, wgcnt, E, nwg);
    k_btot<<<NBKT, 512, 0, stream>>>(wgcnt, tot, nwg);
    k_escan<<<1, 1024, 0, stream>>>(tot, ebase);
    k_bscan<<<NBKT, 512, 0, stream>>>(wgcnt, ebase, base, nwg);
    k_bscatter<<<nwg, BTHREADS, 0, stream>>>(src, dst, base, srt, E, nwg);
    k_bsort<<<NBKT, 256, 0, stream>>>(srt, ebase, srt2, rs, dinv);

    // layer 1
    k_h1<<<tileBlocks, 256, 0, stream>>>(x, W1, dinv, hs);
    k_agg<<<aggBlocks, 256, 0, stream>>>(srt2, rs, dinv, hs, b1, out1);

    // layer 2
    k_h2<<<tileBlocks, 256, 0, stream>>>(out1, W2, dinv, hs);
    k_agg<<<aggBlocks, 256, 0, stream>>>(srt2, rs, dinv, hs, b2, out);
}

// Round 7
// 257.872 us; speedup vs baseline: 3.5063x; 1.1010x over previous
//
#include <hip/hip_runtime.h>
#include <hip/hip_fp16.h>

#define N_NODES 100000
#define F_IN 128
#define HD 16
#define NBKT 782       // buckets of 128 nodes; bucket = dst >> 7
#define NPB 128        // nodes per bucket
#define CHUNK 8192     // edges per workgroup in bucket-build passes (nwg = 391)
#define BTHREADS 512   // threads per build-pass workgroup (8 waves)

typedef __attribute__((ext_vector_type(4))) _Float16 half4;
typedef __attribute__((ext_vector_type(8))) _Float16 half8v;
typedef __attribute__((ext_vector_type(4))) float f32x4;

// ---------- pass 1: per-WG LDS histogram over buckets (NO global atomics) ----------
__global__ __launch_bounds__(BTHREADS) void k_bcnt(const int* __restrict__ dst, int* __restrict__ wgcnt,
                                                   int E, int nwg) {
    __shared__ int hist[NBKT];
    const int t = threadIdx.x, wg = blockIdx.x;
    for (int b = t; b < NBKT; b += BTHREADS) hist[b] = 0;
    __syncthreads();
    const int e0 = wg * CHUNK;
    for (int it = 0; it < CHUNK / (BTHREADS * 4); ++it) {
        int idx = e0 + it * (BTHREADS * 4) + t * 4;
        if (idx + 3 < E) {
            int4 d = *(const int4*)(dst + idx);
            atomicAdd(&hist[d.x >> 7], 1);
            atomicAdd(&hist[d.y >> 7], 1);
            atomicAdd(&hist[d.z >> 7], 1);
            atomicAdd(&hist[d.w >> 7], 1);
        } else {
            int lim = min(idx + 4, E);
            for (int e = idx; e < lim; ++e) atomicAdd(&hist[dst[e] >> 7], 1);
        }
    }
    __syncthreads();
    for (int b = t; b < NBKT; b += BTHREADS) wgcnt[b * nwg + wg] = hist[b];  // bucket-major
}

// ---------- bucket totals (nwg <= 512) ----------
__global__ __launch_bounds__(512) void k_btot(const int* __restrict__ wgcnt, int* __restrict__ tot, int nwg) {
    __shared__ int s[512];
    const int b = blockIdx.x, t = threadIdx.x;
    s[t] = (t < nwg) ? wgcnt[b * nwg + t] : 0;
    __syncthreads();
    for (int off = 256; off > 0; off >>= 1) { if (t < off) s[t] += s[t + off]; __syncthreads(); }
    if (t == 0) tot[b] = s[0];
}

// ---------- exclusive scan of bucket totals (one WG; NBKT=782 < 1024) ----------
__global__ __launch_bounds__(1024) void k_escan(const int* __restrict__ tot, int* __restrict__ ebase) {
    __shared__ int s[1024];
    const int t = threadIdx.x;
    int v = (t < NBKT) ? tot[t] : 0;
    s[t] = v; __syncthreads();
    for (int off = 1; off < 1024; off <<= 1) {
        int x = (t >= off) ? s[t - off] : 0;
        __syncthreads();
        s[t] += x;
        __syncthreads();
    }
    if (t < NBKT) ebase[t] = s[t] - v;       // exclusive
    if (t == NBKT - 1) ebase[NBKT] = s[t];   // total = E
}

// ---------- per-(bucket, wg) base offsets (nwg <= 512) ----------
__global__ __launch_bounds__(512) void k_bscan(const int* __restrict__ wgcnt, const int* __restrict__ ebase,
                                               int* __restrict__ base, int nwg) {
    __shared__ int s[512];
    const int b = blockIdx.x, t = threadIdx.x;
    int v = (t < nwg) ? wgcnt[b * nwg + t] : 0;
    s[t] = v; __syncthreads();
    for (int off = 1; off < 512; off <<= 1) {
        int x = (t >= off) ? s[t - off] : 0;
        __syncthreads();
        s[t] += x;
        __syncthreads();
    }
    if (t < nwg) base[b * nwg + t] = ebase[b] + s[t] - v;
}

// ---------- pass 2: scatter into bucket-sorted order (LDS cursors) ----------
__global__ __launch_bounds__(BTHREADS) void k_bscatter(const int* __restrict__ src, const int* __restrict__ dst,
                                                       const int* __restrict__ base, unsigned* __restrict__ srt,
                                                       int E, int nwg) {
    __shared__ int cur[NBKT];
    const int t = threadIdx.x, wg = blockIdx.x;
    for (int b = t; b < NBKT; b += BTHREADS) cur[b] = base[b * nwg + wg];
    __syncthreads();
    const int e0 = wg * CHUNK;
    for (int it = 0; it < CHUNK / (BTHREADS * 4); ++it) {
        int idx = e0 + it * (BTHREADS * 4) + t * 4;
        if (idx + 3 < E) {
            int4 s4 = *(const int4*)(src + idx);
            int4 d4 = *(const int4*)(dst + idx);
            int p;
            p = atomicAdd(&cur[d4.x >> 7], 1); srt[p] = ((unsigned)s4.x << 7) | (unsigned)(d4.x & 127);
            p = atomicAdd(&cur[d4.y >> 7], 1); srt[p] = ((unsigned)s4.y << 7) | (unsigned)(d4.y & 127);
            p = atomicAdd(&cur[d4.z >> 7], 1); srt[p] = ((unsigned)s4.z << 7) | (unsigned)(d4.z & 127);
            p = atomicAdd(&cur[d4.w >> 7], 1); srt[p] = ((unsigned)s4.w << 7) | (unsigned)(d4.w & 127);
        } else {
            int lim = min(idx + 4, E);
            for (int e = idx; e < lim; ++e) {
                int p = atomicAdd(&cur[dst[e] >> 7], 1);
                srt[p] = ((unsigned)src[e] << 7) | (unsigned)(dst[e] & 127);
            }
        }
    }
}

// ---------- pass 3: in-bucket counting sort -> node-level CSR (srt2, rs, dinv) ----------
__global__ __launch_bounds__(256) void k_bsort(const unsigned* __restrict__ srt,
                                               const int* __restrict__ ebase,
                                               int* __restrict__ srt2,
                                               int* __restrict__ rs,
                                               float* __restrict__ dinv) {
    __shared__ int cnt_s[NPB];
    __shared__ int sc[NPB];
    __shared__ int cur_s[NPB];
    const int t = threadIdx.x, b = blockIdx.x;
    const int beg = ebase[b], end = ebase[b + 1];

    if (t < NPB) cnt_s[t] = 0;
    __syncthreads();
    for (int i = beg + t; i < end; i += 256) atomicAdd(&cnt_s[srt[i] & 127], 1);
    __syncthreads();

    if (t < NPB) sc[t] = cnt_s[t];
    __syncthreads();
    for (int off = 1; off < NPB; off <<= 1) {
        int v = (t < NPB && t >= off) ? sc[t - off] : 0;
        __syncthreads();
        if (t < NPB) sc[t] += v;
        __syncthreads();
    }
    if (t < NPB) {
        int start = beg + sc[t] - cnt_s[t];   // exclusive
        cur_s[t] = start;
        int node = b * NPB + t;
        if (node <= N_NODES) rs[node] = start;  // node==N_NODES (last bucket) -> E
        if (node < N_NODES) dinv[node] = rsqrtf((float)(cnt_s[t] + 1));  // +1 self-loop
    }
    __syncthreads();
    for (int i = beg + t; i < end; i += 256) {
        unsigned p = srt[i];
        int pos = atomicAdd(&cur_s[p & 127], 1);
        srt2[pos] = (int)(p >> 7);            // plain src, dst-sorted
    }
}

// ---------- dense layer 1 (MFMA): hs1 = fp16( dinv * (x @ W1) ) ----------
// One wave computes a 16-node x 16-col tile via 4x mfma_f32_16x16x32_f16 (K=128).
// No LDS. A-frag: lane l holds x[node0+(l&15)][kk*32+(l>>4)*8+j], j=0..7 (two dwordx4).
// B-frag: lane l holds W1[kk*32+(l>>4)*8+j][l&15] (8KB table, L2-hot).
// C/D layout (verified): col = lane&15, node-row = (lane>>4)*4 + reg.
__global__ __launch_bounds__(256) void k_h1(
        const float* __restrict__ x, const float* __restrict__ W1,
        const float* __restrict__ dinv, _Float16* __restrict__ hs) {
    const int wave = threadIdx.x >> 6;
    const int lane = threadIdx.x & 63;
    const int node0 = blockIdx.x * 64 + wave * 16;
    const int col = lane & 15;
    const int koff = (lane >> 4) * 8;

    // B fragments (same for all waves/blocks; W1 is [k][col] row-major)
    half8v bfrag[4];
#pragma unroll
    for (int kk = 0; kk < 4; ++kk) {
#pragma unroll
        for (int j = 0; j < 8; ++j)
            bfrag[kk][j] = (_Float16)W1[(kk * 32 + koff + j) * HD + col];
    }

    const int nrow = node0 + col;                       // A-row this lane loads
    const int crow = (nrow < N_NODES) ? nrow : (N_NODES - 1);
    const float* __restrict__ xr = x + (size_t)crow * F_IN;

    f32x4 acc = {0.0f, 0.0f, 0.0f, 0.0f};
#pragma unroll
    for (int kk = 0; kk < 4; ++kk) {
        float4 xa = *(const float4*)(xr + kk * 32 + koff);
        float4 xb = *(const float4*)(xr + kk * 32 + koff + 4);
        half8v a;
        a[0] = (_Float16)xa.x; a[1] = (_Float16)xa.y;
        a[2] = (_Float16)xa.z; a[3] = (_Float16)xa.w;
        a[4] = (_Float16)xb.x; a[5] = (_Float16)xb.y;
        a[6] = (_Float16)xb.z; a[7] = (_Float16)xb.w;
        acc = __builtin_amdgcn_mfma_f32_16x16x32_f16(a, bfrag[kk], acc, 0, 0, 0);
    }

#pragma unroll
    for (int r = 0; r < 4; ++r) {
        int n = node0 + (lane >> 4) * 4 + r;
        if (n < N_NODES)
            hs[n * HD + col] = (_Float16)(acc[r] * dinv[n]);
    }
}

// ---------- dense layer 2: hs2 = fp16( dinv * (relu(out1) @ W2) ) ----------
__global__ __launch_bounds__(256) void k_h2(
        const float* __restrict__ out1, const float* __restrict__ W2,
        const float* __restrict__ dinv, _Float16* __restrict__ hs) {
    __shared__ float ws[HD * HD];
    __shared__ float as[16][HD + 1];
    const int t = threadIdx.x;
    const int node0 = blockIdx.x * 16;

    if (t < HD * HD) ws[t] = W2[t];
    {
        int n = node0 + (t >> 4);
        float v = (n < N_NODES) ? out1[node0 * HD + t] : 0.0f;
        as[t >> 4][t & 15] = fmaxf(v, 0.0f);
    }
    __syncthreads();

    const int row = t >> 4, col = t & 15;
    const int node = node0 + row;
    float acc = 0.0f;
#pragma unroll
    for (int k = 0; k < HD; ++k)
        acc += as[row][k] * ws[k * HD + col];

    if (node < N_NODES) hs[node * HD + col] = (_Float16)(acc * dinv[node]);
}

// ---------- aggregation: one wave per node, fp16 gathers, f32 accumulate ----------
// 16 edge-slots x 4-lane 8B feature-quads = 16 outstanding 32B row-gathers/wave.
// out[d] = dinv[d] * ( sum_{s in N(d)} hs[s] + hs[d] ) + bias
__global__ __launch_bounds__(256) void k_agg(
        const int* __restrict__ srt2, const int* __restrict__ rs,
        const float* __restrict__ dinv, const _Float16* __restrict__ hs,
        const float* __restrict__ bias, float* __restrict__ out) {
    const int node = blockIdx.x * 4 + (threadIdx.x >> 6);
    if (node >= N_NODES) return;   // wave-uniform
    const int lane = threadIdx.x & 63;
    const int slot = lane >> 2;    // 16 edge slots
    const int c4 = lane & 3;       // feature quad (4 halves = 8B)

    const int beg = rs[node];
    const int n   = rs[node + 1] - beg;
    const half4* __restrict__ h4 = (const half4*)hs;

    float ax = 0.0f, ay = 0.0f, az = 0.0f, aw = 0.0f;
    for (int i = slot; i < n; i += 16) {
        int s = srt2[beg + i];         // 16 slots read 64B coalesced; broadcast within quad
        half4 v = h4[s * 4 + c4];      // 4 lanes fetch one contiguous 32B row
        ax += (float)v.x; ay += (float)v.y; az += (float)v.z; aw += (float)v.w;
    }
#pragma unroll
    for (int m = 4; m <= 32; m <<= 1) {
        ax += __shfl_xor(ax, m);
        ay += __shfl_xor(ay, m);
        az += __shfl_xor(az, m);
        aw += __shfl_xor(aw, m);
    }
    if (slot == 0) {
        half4 hv = h4[node * 4 + c4];
        float4 bb = ((const float4*)bias)[c4];
        float dd = dinv[node];
        float4 o;
        o.x = dd * (ax + (float)hv.x) + bb.x;
        o.y = dd * (ay + (float)hv.y) + bb.y;
        o.z = dd * (az + (float)hv.z) + bb.z;
        o.w = dd * (aw + (float)hv.w) + bb.w;
        ((float4*)out)[node * 4 + c4] = o;
    }
}

// ---------------- launch ----------------
extern "C" void kernel_launch(void* const* d_in, const int* in_sizes, int n_in,
                              void* d_out, int out_size, void* d_ws, size_t ws_size,
                              hipStream_t stream) {
    const float* x   = (const float*)d_in[0];
    const int*   ei  = (const int*)d_in[1];
    const float* W1  = (const float*)d_in[2];
    const float* b1  = (const float*)d_in[3];
    const float* W2  = (const float*)d_in[4];
    const float* b2  = (const float*)d_in[5];
    float* out = (float*)d_out;

    const int E = in_sizes[1] / 2;
    const int* src = ei;
    const int* dst = ei + E;
    const int nwg = (E + CHUNK - 1) / CHUNK;   // 391 for E=3.2M

    // workspace layout (bytes). Aliasing:
    //  - srt  [0x100000, +12.8MB) is dead after k_bsort; hs (fp16, 3.2MB) and
    //    out1 (f32, 6.4MB) reuse its region afterwards.
    //  - wgcnt/base live inside srt2's region; both dead before k_bsort writes srt2.
    char* wsb = (char*)d_ws;
    int*      tot   = (int*)(wsb + 0x0000000);      // NBKT ints
    int*      ebase = (int*)(wsb + 0x0001000);      // NBKT+1 ints
    float*    dinv  = (float*)(wsb + 0x0002000);    // 400 KB
    int*      rs    = (int*)(wsb + 0x0070000);      // (N+1) ints, 400 KB
    unsigned* srt   = (unsigned*)(wsb + 0x0100000); // 12.8 MB packed edges
    _Float16* hs    = (_Float16*)(wsb + 0x0100000); // 3.2 MB (aliases srt, written after k_bsort)
    float*    out1  = (float*)(wsb + 0x0500000);    // 6.4 MB (aliases srt tail)
    int*      srt2  = (int*)(wsb + 0x0D40000);      // 12.8 MB dst-sorted src
    int*      wgcnt = (int*)(wsb + 0x0D40000);      // NBKT*nwg ints (~1.2 MB; dead before srt2 written)
    int*      base  = (int*)(wsb + 0x0F00000);      // NBKT*nwg ints (~1.2 MB; dead before srt2 written)

    const int h1Blocks   = (N_NODES + 63) / 64;     // 64 nodes per block (4 MFMA waves)
    const int tileBlocks = (N_NODES + 15) / 16;
    const int aggBlocks  = (N_NODES + 3) / 4;

    // node-CSR build (atomic-free at global scope; reused by both layers)
    k_bcnt<<<nwg, BTHREADS, 0, stream>>>(dst, wgcnt, E, nwg);
    k_btot<<<NBKT, 512, 0, stream>>>(wgcnt, tot, nwg);
    k_escan<<<1, 1024, 0, stream>>>(tot, ebase);
    k_bscan<<<NBKT, 512, 0, stream>>>(wgcnt, ebase, base, nwg);
    k_bscatter<<<nwg, BTHREADS, 0, stream>>>(src, dst, base, srt, E, nwg);
    k_bsort<<<NBKT, 256, 0, stream>>>(srt, ebase, srt2, rs, dinv);

    // layer 1
    k_h1<<<h1Blocks, 256, 0, stream>>>(x, W1, dinv, hs);
    k_agg<<<aggBlocks, 256, 0, stream>>>(srt2, rs, dinv, hs, b1, out1);

    // layer 2
    k_h2<<<tileBlocks, 256, 0, stream>>>(out1, W2, dinv, hs);
    k_agg<<<aggBlocks, 256, 0, stream>>>(srt2, rs, dinv, hs, b2, out);
}